// Round 7
// baseline (534.299 us; speedup 1.0000x reference)
//
#include <hip/hip_runtime.h>
#include <stdint.h>

// WindowedAttn on MI355X (gfx950)
// Pipeline: cast x->bf16 | transpose W_qkv,W_out -> bf16 B^T
//           | GEMM1 -> Q,K into qk[tok][4096] AND V transposed into vt[d][tok]
//           | flash attention per 128-q tile (S^T / O^T trick, V^T staged via
//             global_load_lds double-buffered)
//           | GEMM2 (fp32 out)
// GEMMs: round-0 128x128 block tile, BK=64, global_load_lds width=16,
// XOR-swizzled LDS (chunk ^ (row&7)) -> conflict-free ds_read_b128.
// R6: attn softmax VALU diet -- (a) log2-domain (scores pre-scaled by
// SCALE*log2e, __builtin_amdgcn_exp2f = bare v_exp_f32), (b) v_cvt_pk_bf16_f32
// for P->bf16 pack (T12 recipe; 8 ops replace ~70 of manual-RNE f2b+or),
// (c) defer-max with THR=12 wave-vote (T13): O-rescale only when running max
// grows >12 in log2 domain (P bounded by 2^12; rare on random data).
// (R6 first attempt used __exp2f -> glibc math.h macro collision; now using
// the direct intrinsic.)

typedef unsigned short u16;
typedef unsigned int u32;
typedef __attribute__((ext_vector_type(8))) short bf16x8;   // 8 bf16 = 4 VGPRs
typedef __attribute__((ext_vector_type(4))) float f32x4;

#define QKN 4096   // Q,K buffer row stride
#define DM 2048

__device__ __forceinline__ u16 f2b(float f) {
  u32 u = __builtin_bit_cast(u32, f);
  u32 r = (u + 0x7fffu + ((u >> 16) & 1u)) >> 16;  // RNE
  return (u16)r;
}

// pack two f32 -> two bf16 (RNE), lo in bits[15:0]
__device__ __forceinline__ u32 cvt_pk_bf16(float lo, float hi) {
  u32 r;
  asm("v_cvt_pk_bf16_f32 %0, %1, %2" : "=v"(r) : "v"(lo), "v"(hi));
  return r;
}

__device__ __forceinline__ void gload_lds16(const void* g, void* l) {
  __builtin_amdgcn_global_load_lds((const __attribute__((address_space(1))) void*)g,
                                   (__attribute__((address_space(3))) void*)l,
                                   16, 0, 0);
}

// ---------------- prep kernels ----------------

__global__ void cast_f32_bf16(const float4* __restrict__ x, uint4* __restrict__ o) {
  int idx = blockIdx.x * 256 + threadIdx.x;   // grid sized exactly: n/8 threads
  float4 a = x[2 * idx];
  float4 b = x[2 * idx + 1];
  uint4 r;
  r.x = (u32)f2b(a.x) | ((u32)f2b(a.y) << 16);
  r.y = (u32)f2b(a.z) | ((u32)f2b(a.w) << 16);
  r.z = (u32)f2b(b.x) | ((u32)f2b(b.y) << 16);
  r.w = (u32)f2b(b.z) | ((u32)f2b(b.w) << 16);
  o[idx] = r;
}

// W (K x N, fp32, row-major) -> Wt (N x K, bf16, row-major)
__global__ void transpose_cast(const float* __restrict__ W, u16* __restrict__ Wt,
                               int K, int N) {
  __shared__ u16 tile[64][65];
  int tx = threadIdx.x & 63;
  int ty = threadIdx.x >> 6;
  int n0 = blockIdx.x * 64;
  int k0 = blockIdx.y * 64;
#pragma unroll
  for (int r = 0; r < 64; r += 4)
    tile[r + ty][tx] = f2b(W[(size_t)(k0 + r + ty) * N + n0 + tx]);
  __syncthreads();
#pragma unroll
  for (int r = 0; r < 64; r += 4)
    Wt[(size_t)(n0 + r + ty) * K + k0 + tx] = tile[tx][r + ty];
}

// ---------------- GEMM: C[M][N] = A[M][K] * Bt[N][K]^T + bias ----------------
// block 256 = 4 waves (2x2 of 64x64), 4x4 16x16x32 mfma per wave.
// Columns >= vstart are written TRANSPOSED to vt[col-vstart][row] (V^T for attn);
// n0 is 128-aligned so the branch is uniform per block.

template <typename TO>
__global__ __launch_bounds__(256, 3) void gemm_bt(const u16* __restrict__ A,
                                                  const u16* __restrict__ Bt,
                                                  const float* __restrict__ bias,
                                                  TO* __restrict__ C,
                                                  u16* __restrict__ vt,
                                                  int M, int N, int K,
                                                  int crstride, int vstart) {
  __shared__ u16 As[128 * 64];
  __shared__ u16 Bs[128 * 64];
  const int tid = threadIdx.x;
  const int lane = tid & 63;
  const int wave = tid >> 6;
  const int quad = lane >> 4;
  const int l15 = lane & 15;
  const int m0 = blockIdx.y * 128;
  const int n0 = blockIdx.x * 128;
  const int wm = (wave & 1) * 64;
  const int wn = (wave >> 1) * 64;

  f32x4 acc[4][4] = {};

  for (int k0 = 0; k0 < K; k0 += 64) {
    // stage A,B tiles: row = 128B = 8 chunks of 16B; stored chunk c' = c ^ (row&7)
#pragma unroll
    for (int i = 0; i < 4; ++i) {
      int sb = wave * 256 + i * 64;     // wave-uniform slot base
      int s = sb + lane;                // slot = row*8 + c'
      int m = s >> 3;
      int c = (s & 7) ^ (m & 7);        // global chunk to fetch for this slot
      gload_lds16(A + (size_t)(m0 + m) * K + (k0 + c * 8), As + sb * 8);
      gload_lds16(Bt + (size_t)(n0 + m) * K + (k0 + c * 8), Bs + sb * 8);
    }
    __syncthreads();
#pragma unroll
    for (int ks = 0; ks < 2; ++ks) {
      bf16x8 af[4], bf[4];
#pragma unroll
      for (int i = 0; i < 4; ++i) {
        int m = wm + i * 16 + l15;
        af[i] = *(const bf16x8*)(As + m * 64 + (((ks * 4 + quad) ^ (m & 7)) << 3));
        int n = wn + i * 16 + l15;
        bf[i] = *(const bf16x8*)(Bs + n * 64 + (((ks * 4 + quad) ^ (n & 7)) << 3));
      }
#pragma unroll
      for (int i = 0; i < 4; ++i)
#pragma unroll
        for (int j = 0; j < 4; ++j)
          acc[i][j] = __builtin_amdgcn_mfma_f32_16x16x32_bf16(af[i], bf[j], acc[i][j], 0, 0, 0);
    }
    __syncthreads();
  }

  // epilogue: D row=(quad*4+t), col=l15 (m89-verified)
  if (n0 >= vstart) {
    // V block: write transposed vt[d][token], 4 consecutive tokens packed -> 8B store
#pragma unroll
    for (int j = 0; j < 4; ++j) {
      int col = n0 + wn + j * 16 + l15;
      float bv = bias[col];
      u16* vcol = vt + (size_t)(col - vstart) * 8192;
#pragma unroll
      for (int i = 0; i < 4; ++i) {
        int row = m0 + wm + i * 16 + quad * 4;
        uint2 pk;
        pk.x = (u32)f2b(acc[i][j][0] + bv) | ((u32)f2b(acc[i][j][1] + bv) << 16);
        pk.y = (u32)f2b(acc[i][j][2] + bv) | ((u32)f2b(acc[i][j][3] + bv) << 16);
        *(uint2*)(vcol + row) = pk;
      }
    }
  } else {
#pragma unroll
    for (int j = 0; j < 4; ++j) {
      int col = n0 + wn + j * 16 + l15;
      float bv = bias[col];
#pragma unroll
      for (int i = 0; i < 4; ++i) {
        int row = m0 + wm + i * 16 + quad * 4;
#pragma unroll
        for (int t = 0; t < 4; ++t) {
          float v = acc[i][j][t] + bv;
          if constexpr (sizeof(TO) == 2)
            C[(size_t)(row + t) * crstride + col] = (TO)f2b(v);
          else
            C[(size_t)(row + t) * crstride + col] = (TO)v;
        }
      }
    }
  }
}

// ---------------- attention ----------------
// One block per (b, h, win, qtile of 128). kk-tiles of 64.
// S^T = K * Q^T  (A-frag: K rows from global; B-frag: Q rows from global)
// O^T += V^T * P^T (A-frag: Vs LDS [d][kk] staged from global vt via
// global_load_lds, double-buffered + prefetched one jt ahead; B-frag: Ps LDS
// [q][kk]) -- both XOR-swizzled, conflict-free ds_read_b128.
// Softmax in log2 domain: s2 = score*SCALE*log2e, p = 2^(s2 - m2). Identical
// values to exp-domain (m2 = max s2), but exp2 is the bare HW op.

__global__ __launch_bounds__(256, 2) void attn_win(const u16* __restrict__ qk,
                                                   const u16* __restrict__ vt,
                                                   u16* __restrict__ attn_out) {
  __shared__ u16 Vs[2][8192];   // [d=128][kk=64], chunk ^ (d&7), double-buffered
  __shared__ u16 Ps[128 * 64];  // [q][kk], chunk ^ (q&7)
  const int tid = threadIdx.x;
  const int lane = tid & 63;
  const int wave = tid >> 6;
  const int quad = lane >> 4;
  const int l15 = lane & 15;
  const int qt = blockIdx.x;        // 0..3
  const int win = blockIdx.y;       // 0..7
  const int b = blockIdx.z >> 4;
  const int h = blockIdx.z & 15;
  const int tokw = b * 4096 + win * 512;
  const int tokq = tokw + qt * 128;
  const float CL2E = 0.12751743f;   // (1/sqrt(128)) * log2(e)
  const float THR = 12.0f;          // defer-max threshold (log2 domain): P <= 2^12

  // stage V^T tile for kk-tile jt into Vs[buf]
  auto stageV = [&](int jt, int buf) {
    const u16* vbase = vt + (size_t)(h * 128) * 8192 + (tokw + jt * 64);
    char* dst0 = (char*)Vs[buf] + wave * 1024;
#pragma unroll
    for (int it = 0; it < 4; ++it) {
      int ch = it * 256 + wave * 64 + lane;   // 1024 chunks of 16B
      int row = ch >> 3;
      int c = (ch & 7) ^ (row & 7);
      gload_lds16(vbase + (size_t)row * 8192 + c * 8, dst0 + it * 4096);
    }
  };

  stageV(0, 0);

  // Q fragments (kept in registers for the whole block)
  bf16x8 qf[2][4];
  {
    const u16* Qb = qk + (size_t)tokq * QKN + h * 128;
#pragma unroll
    for (int j = 0; j < 2; ++j) {
      const u16* Qr = Qb + (size_t)(wave * 32 + j * 16 + l15) * QKN + quad * 8;
#pragma unroll
      for (int ks = 0; ks < 4; ++ks)
        qf[j][ks] = *(const bf16x8*)(Qr + ks * 32);
    }
  }

  f32x4 acc_o[8][2] = {};
  float mrun[2] = {-1e30f, -1e30f};
  float lrun[2] = {0.f, 0.f};

  const int jt_end = 2 * qt + 1;
  for (int jt = 0; jt <= jt_end; ++jt) {
    // prefetch next V^T tile into the other buffer (drained by the
    // end-of-iteration barrier, visible to all waves there)
    if (jt < jt_end) stageV(jt + 1, (jt + 1) & 1);

    // ---- S^T = K * Q^T ----
    f32x4 acc_s[4][2] = {};
    {
      const u16* Kb = qk + (size_t)(tokw + jt * 64) * QKN + 2048 + h * 128;
      bf16x8 kf[4][4];
#pragma unroll
      for (int i = 0; i < 4; ++i) {
        const u16* Kr = Kb + (size_t)(i * 16 + l15) * QKN + quad * 8;
#pragma unroll
        for (int ks = 0; ks < 4; ++ks)
          kf[i][ks] = *(const bf16x8*)(Kr + ks * 32);
      }
#pragma unroll
      for (int ks = 0; ks < 4; ++ks)
#pragma unroll
        for (int i = 0; i < 4; ++i)
#pragma unroll
          for (int j = 0; j < 2; ++j)
            acc_s[i][j] = __builtin_amdgcn_mfma_f32_16x16x32_bf16(kf[i][ks], qf[j][ks],
                                                                  acc_s[i][j], 0, 0, 0);
    }

    // ---- online softmax (log2 domain; per-lane state; q fixed per lane) ----
    const bool need_mask = (jt >= 2 * qt);
#pragma unroll
    for (int j = 0; j < 2; ++j) {
      int ql = wave * 32 + j * 16 + l15;  // q local in 128-tile
      int qg = qt * 128 + ql;             // q in window
      float vmax = -1e30f;
#pragma unroll
      for (int i = 0; i < 4; ++i)
#pragma unroll
        for (int t = 0; t < 4; ++t) {
          float s = acc_s[i][j][t] * CL2E;
          if (need_mask) {
            int kg = jt * 64 + i * 16 + quad * 4 + t;
            if (kg > qg) s = -1e30f;
          }
          acc_s[i][j][t] = s;
          vmax = fmaxf(vmax, s);
        }
      vmax = fmaxf(vmax, __shfl_xor(vmax, 16));
      vmax = fmaxf(vmax, __shfl_xor(vmax, 32));
      // defer-max (T13): rescale only when some lane's max outgrew the running
      // max by > THR. Otherwise keep mrun; P values bounded by 2^THR.
      if (__any(vmax > mrun[j] + THR)) {
        float mnew = fmaxf(mrun[j], vmax);
        float alpha = __builtin_amdgcn_exp2f(mrun[j] - mnew);
        mrun[j] = mnew;
        lrun[j] *= alpha;
#pragma unroll
        for (int i2 = 0; i2 < 8; ++i2)
#pragma unroll
          for (int t = 0; t < 4; ++t)
            acc_o[i2][j][t] *= alpha;
      }
      float mnew = mrun[j];
      float vsum = 0.f;
#pragma unroll
      for (int i = 0; i < 4; ++i) {
        float p0 = __builtin_amdgcn_exp2f(acc_s[i][j][0] - mnew);
        float p1 = __builtin_amdgcn_exp2f(acc_s[i][j][1] - mnew);
        float p2 = __builtin_amdgcn_exp2f(acc_s[i][j][2] - mnew);
        float p3 = __builtin_amdgcn_exp2f(acc_s[i][j][3] - mnew);
        vsum += (p0 + p1) + (p2 + p3);
        uint2 pk;
        pk.x = cvt_pk_bf16(p0, p1);
        pk.y = cvt_pk_bf16(p2, p3);
        int kk = i * 16 + quad * 4;
        *(uint2*)((char*)Ps + ql * 128 + (((kk >> 3) ^ (ql & 7)) << 4) + ((kk & 7) << 1)) = pk;
      }
      vsum += __shfl_xor(vsum, 16);
      vsum += __shfl_xor(vsum, 32);
      lrun[j] += vsum;
    }
    __syncthreads();  // Vs[jt&1] staged (prev iter) + Ps written

    // ---- O^T += V^T * P^T ----
    const u16* Vtile = Vs[jt & 1];
#pragma unroll
    for (int ks = 0; ks < 2; ++ks) {
      int kk = ks * 32 + quad * 8;
      int kc = kk >> 3;
      bf16x8 pf[2];
#pragma unroll
      for (int j = 0; j < 2; ++j) {
        int ql = wave * 32 + j * 16 + l15;
        pf[j] = *(const bf16x8*)((char*)Ps + ql * 128 + ((kc ^ (ql & 7)) << 4));
      }
#pragma unroll
      for (int i2 = 0; i2 < 8; ++i2) {
        int d = i2 * 16 + l15;
        bf16x8 vf = *(const bf16x8*)((char*)Vtile + d * 128 + ((kc ^ (d & 7)) << 4));
#pragma unroll
        for (int j = 0; j < 2; ++j)
          acc_o[i2][j] = __builtin_amdgcn_mfma_f32_16x16x32_bf16(vf, pf[j], acc_o[i2][j], 0, 0, 0);
      }
    }
    __syncthreads();  // protect Vs/Ps for next jt
  }

  // ---- epilogue: O^T C-layout -> attn_out[tok][h*128+d], 4 contiguous d per store ----
#pragma unroll
  for (int j = 0; j < 2; ++j) {
    float inv = 1.0f / lrun[j];
    int ql = wave * 32 + j * 16 + l15;
    u16* orow = attn_out + (size_t)(tokq + ql) * DM + h * 128;
#pragma unroll
    for (int i2 = 0; i2 < 8; ++i2) {
      int d = i2 * 16 + quad * 4;
      uint2 pk;
      pk.x = cvt_pk_bf16(acc_o[i2][j][0] * inv, acc_o[i2][j][1] * inv);
      pk.y = cvt_pk_bf16(acc_o[i2][j][2] * inv, acc_o[i2][j][3] * inv);
      *(uint2*)(orow + d) = pk;
    }
  }
}

// ---------------- launch ----------------

extern "C" void kernel_launch(void* const* d_in, const int* in_sizes, int n_in,
                              void* d_out, int out_size, void* d_ws, size_t ws_size,
                              hipStream_t stream) {
  const float* x = (const float*)d_in[0];
  const float* W_qkv = (const float*)d_in[1];
  const float* b_qkv = (const float*)d_in[2];
  const float* W_out = (const float*)d_in[3];
  const float* b_out = (const float*)d_in[4];
  float* out = (float*)d_out;

  char* w = (char*)d_ws;
  u16* xb = (u16*)w;                              // 32MB [8192][2048]; reused as attn_out
  u16* wqkvT = (u16*)(w + (32u << 20));           // 24MB [6144][2048]
  u16* woutT = (u16*)(w + (56u << 20));           // 8MB  [2048][2048]
  u16* qk = (u16*)(w + (64u << 20));              // 64MB [8192][4096]  (Q,K)
  u16* vtb = (u16*)(w + (128u << 20));            // 32MB [2048][8192]  (V^T)

  cast_f32_bf16<<<8192, 256, 0, stream>>>((const float4*)x, (uint4*)xb);
  transpose_cast<<<dim3(96, 32), 256, 0, stream>>>(W_qkv, wqkvT, 2048, 6144);
  transpose_cast<<<dim3(32, 32), 256, 0, stream>>>(W_out, woutT, 2048, 2048);
  gemm_bt<u16><<<dim3(48, 64), 256, 0, stream>>>(xb, wqkvT, b_qkv, qk, vtb,
                                                 8192, 6144, 2048, 4096, 4096);
  attn_win<<<dim3(4, 8, 32), 256, 0, stream>>>(qk, vtb, xb);
  gemm_bt<float><<<dim3(16, 64), 256, 0, stream>>>(xb, woutT, b_out, out, vtb,
                                                   8192, 2048, 2048, 2048, 1 << 28);
}

// Round 8
// 485.125 us; speedup vs baseline: 1.1014x; 1.1014x over previous
//
#include <hip/hip_runtime.h>
#include <stdint.h>

// WindowedAttn on MI355X (gfx950)
// Pipeline: cast x->bf16 | transpose W_qkv,W_out -> bf16 B^T
//           | GEMM1 -> Q,K into qk[tok][4096] AND V transposed into vt[d][tok]
//           | flash attention per 128-q tile (S^T / O^T trick)
//           | GEMM2 (fp32 out)
// GEMMs: 128x128 block tile, BK=64, global_load_lds width=16, XOR-swizzled LDS.
// R8 attn: (a) K-tile now STAGED IN LDS (double-buffered, global_load_lds,
// pre-swizzled source) -- was 4x-redundant per-wave global loads on the QK^T
// critical path; (b) qt-PAIRING: block x in {0,1} runs q-tiles {x, 3-x}
// sequentially -> every block does exactly 10 jt-units (was 2..8, tail-bound).
// Softmax: log2-domain + v_cvt_pk_bf16_f32 + defer-max THR=12 (R6).

typedef unsigned short u16;
typedef unsigned int u32;
typedef __attribute__((ext_vector_type(8))) short bf16x8;   // 8 bf16 = 4 VGPRs
typedef __attribute__((ext_vector_type(4))) float f32x4;

#define QKN 4096   // Q,K buffer row stride
#define DM 2048

__device__ __forceinline__ u16 f2b(float f) {
  u32 u = __builtin_bit_cast(u32, f);
  u32 r = (u + 0x7fffu + ((u >> 16) & 1u)) >> 16;  // RNE
  return (u16)r;
}

// pack two f32 -> two bf16 (RNE), lo in bits[15:0]
__device__ __forceinline__ u32 cvt_pk_bf16(float lo, float hi) {
  u32 r;
  asm("v_cvt_pk_bf16_f32 %0, %1, %2" : "=v"(r) : "v"(lo), "v"(hi));
  return r;
}

__device__ __forceinline__ void gload_lds16(const void* g, void* l) {
  __builtin_amdgcn_global_load_lds((const __attribute__((address_space(1))) void*)g,
                                   (__attribute__((address_space(3))) void*)l,
                                   16, 0, 0);
}

// ---------------- prep kernels ----------------

__global__ void cast_f32_bf16(const float4* __restrict__ x, uint4* __restrict__ o) {
  int idx = blockIdx.x * 256 + threadIdx.x;   // grid sized exactly: n/8 threads
  float4 a = x[2 * idx];
  float4 b = x[2 * idx + 1];
  uint4 r;
  r.x = (u32)f2b(a.x) | ((u32)f2b(a.y) << 16);
  r.y = (u32)f2b(a.z) | ((u32)f2b(a.w) << 16);
  r.z = (u32)f2b(b.x) | ((u32)f2b(b.y) << 16);
  r.w = (u32)f2b(b.z) | ((u32)f2b(b.w) << 16);
  o[idx] = r;
}

// W (K x N, fp32, row-major) -> Wt (N x K, bf16, row-major)
__global__ void transpose_cast(const float* __restrict__ W, u16* __restrict__ Wt,
                               int K, int N) {
  __shared__ u16 tile[64][65];
  int tx = threadIdx.x & 63;
  int ty = threadIdx.x >> 6;
  int n0 = blockIdx.x * 64;
  int k0 = blockIdx.y * 64;
#pragma unroll
  for (int r = 0; r < 64; r += 4)
    tile[r + ty][tx] = f2b(W[(size_t)(k0 + r + ty) * N + n0 + tx]);
  __syncthreads();
#pragma unroll
  for (int r = 0; r < 64; r += 4)
    Wt[(size_t)(n0 + r + ty) * K + k0 + tx] = tile[tx][r + ty];
}

// ---------------- GEMM: C[M][N] = A[M][K] * Bt[N][K]^T + bias ----------------
// block 256 = 4 waves (2x2 of 64x64), 4x4 16x16x32 mfma per wave.
// Columns >= vstart are written TRANSPOSED to vt[col-vstart][row] (V^T for attn);
// n0 is 128-aligned so the branch is uniform per block.

template <typename TO>
__global__ __launch_bounds__(256, 3) void gemm_bt(const u16* __restrict__ A,
                                                  const u16* __restrict__ Bt,
                                                  const float* __restrict__ bias,
                                                  TO* __restrict__ C,
                                                  u16* __restrict__ vt,
                                                  int M, int N, int K,
                                                  int crstride, int vstart) {
  __shared__ u16 As[128 * 64];
  __shared__ u16 Bs[128 * 64];
  const int tid = threadIdx.x;
  const int lane = tid & 63;
  const int wave = tid >> 6;
  const int quad = lane >> 4;
  const int l15 = lane & 15;
  const int m0 = blockIdx.y * 128;
  const int n0 = blockIdx.x * 128;
  const int wm = (wave & 1) * 64;
  const int wn = (wave >> 1) * 64;

  f32x4 acc[4][4] = {};

  for (int k0 = 0; k0 < K; k0 += 64) {
    // stage A,B tiles: row = 128B = 8 chunks of 16B; stored chunk c' = c ^ (row&7)
#pragma unroll
    for (int i = 0; i < 4; ++i) {
      int sb = wave * 256 + i * 64;     // wave-uniform slot base
      int s = sb + lane;                // slot = row*8 + c'
      int m = s >> 3;
      int c = (s & 7) ^ (m & 7);        // global chunk to fetch for this slot
      gload_lds16(A + (size_t)(m0 + m) * K + (k0 + c * 8), As + sb * 8);
      gload_lds16(Bt + (size_t)(n0 + m) * K + (k0 + c * 8), Bs + sb * 8);
    }
    __syncthreads();
#pragma unroll
    for (int ks = 0; ks < 2; ++ks) {
      bf16x8 af[4], bf[4];
#pragma unroll
      for (int i = 0; i < 4; ++i) {
        int m = wm + i * 16 + l15;
        af[i] = *(const bf16x8*)(As + m * 64 + (((ks * 4 + quad) ^ (m & 7)) << 3));
        int n = wn + i * 16 + l15;
        bf[i] = *(const bf16x8*)(Bs + n * 64 + (((ks * 4 + quad) ^ (n & 7)) << 3));
      }
#pragma unroll
      for (int i = 0; i < 4; ++i)
#pragma unroll
        for (int j = 0; j < 4; ++j)
          acc[i][j] = __builtin_amdgcn_mfma_f32_16x16x32_bf16(af[i], bf[j], acc[i][j], 0, 0, 0);
    }
    __syncthreads();
  }

  // epilogue: D row=(quad*4+t), col=l15 (m89-verified)
  if (n0 >= vstart) {
    // V block: write transposed vt[d][token], 4 consecutive tokens packed -> 8B store
#pragma unroll
    for (int j = 0; j < 4; ++j) {
      int col = n0 + wn + j * 16 + l15;
      float bv = bias[col];
      u16* vcol = vt + (size_t)(col - vstart) * 8192;
#pragma unroll
      for (int i = 0; i < 4; ++i) {
        int row = m0 + wm + i * 16 + quad * 4;
        uint2 pk;
        pk.x = (u32)f2b(acc[i][j][0] + bv) | ((u32)f2b(acc[i][j][1] + bv) << 16);
        pk.y = (u32)f2b(acc[i][j][2] + bv) | ((u32)f2b(acc[i][j][3] + bv) << 16);
        *(uint2*)(vcol + row) = pk;
      }
    }
  } else {
#pragma unroll
    for (int j = 0; j < 4; ++j) {
      int col = n0 + wn + j * 16 + l15;
      float bv = bias[col];
#pragma unroll
      for (int i = 0; i < 4; ++i) {
        int row = m0 + wm + i * 16 + quad * 4;
#pragma unroll
        for (int t = 0; t < 4; ++t) {
          float v = acc[i][j][t] + bv;
          if constexpr (sizeof(TO) == 2)
            C[(size_t)(row + t) * crstride + col] = (TO)f2b(v);
          else
            C[(size_t)(row + t) * crstride + col] = (TO)v;
        }
      }
    }
  }
}

// ---------------- attention ----------------
// One block per (pair, win, b*16+h); pair x runs q-tiles {x, 3-x} sequentially
// (uniform 10 jt-units per block). kk-tiles of 64.
// S^T = K * Q^T: kf from Ks LDS [kk=64][d=128] (16 chunks/row, swizzled
// c' = (c&8)|((c&7)^(row&7))), staged via global_load_lds, double-buffered.
// O^T += V^T * P^T: vf from Vs LDS [d][kk] (8 chunks/row, c^(d&7)); pf from Ps.
// All ds_read_b128 conflict-free.

__global__ __launch_bounds__(256, 2) void attn_win(const u16* __restrict__ qk,
                                                   const u16* __restrict__ vt,
                                                   u16* __restrict__ attn_out) {
  __shared__ u16 Ks[2][8192];   // [kk=64][d=128], 16 chunks/row, dbuf (32KB)
  __shared__ u16 Vs[2][8192];   // [d=128][kk=64],  8 chunks/row, dbuf (32KB)
  __shared__ u16 Ps[128 * 64];  // [q][kk], chunk ^ (q&7) (16KB)
  const int tid = threadIdx.x;
  const int lane = tid & 63;
  const int wave = tid >> 6;
  const int quad = lane >> 4;
  const int l15 = lane & 15;
  const int win = blockIdx.y;       // 0..7
  const int b = blockIdx.z >> 4;
  const int h = blockIdx.z & 15;
  const int tokw = b * 4096 + win * 512;
  const float CL2E = 0.12751743f;   // (1/sqrt(128)) * log2(e)
  const float THR = 12.0f;          // defer-max threshold (log2): P <= 2^12

  // stage V^T tile (rows d, 8x16B chunks/row, src chunk = c' ^ (d&7))
  auto stageV = [&](int jt, int buf) {
    const u16* vbase = vt + (size_t)(h * 128) * 8192 + (tokw + jt * 64);
    char* dst0 = (char*)Vs[buf] + wave * 1024;
#pragma unroll
    for (int it = 0; it < 4; ++it) {
      int ch = it * 256 + wave * 64 + lane;   // 1024 chunks of 16B
      int row = ch >> 3;
      int c = (ch & 7) ^ (row & 7);
      gload_lds16(vbase + (size_t)row * 8192 + c * 8, dst0 + it * 4096);
    }
  };
  // stage K tile (rows kk, 16x16B chunks/row, src chunk = (c'&8)|((c'&7)^(kk&7)))
  auto stageK = [&](int jt, int buf) {
    const u16* kbase = qk + (size_t)(tokw + jt * 64) * QKN + 2048 + h * 128;
    char* dst0 = (char*)Ks[buf] + wave * 1024;
#pragma unroll
    for (int it = 0; it < 4; ++it) {
      int ch = it * 256 + wave * 64 + lane;   // 1024 chunks of 16B
      int row = ch >> 4;
      int c16 = ch & 15;
      int c = (c16 & 8) | ((c16 & 7) ^ (row & 7));
      gload_lds16(kbase + (size_t)row * QKN + c * 8, dst0 + it * 4096);
    }
  };

  const int rx = l15 & 7;   // row&7 for all fragment rows (i*16+l15)

  for (int half = 0; half < 2; ++half) {
    const int qt = half == 0 ? (int)blockIdx.x : 3 - (int)blockIdx.x;  // {x,3-x}
    const int tokq = tokw + qt * 128;
    const int jt_end = 2 * qt + 1;

    stageK(0, 0);
    stageV(0, 0);

    // Q fragments (registers for the whole half)
    bf16x8 qf[2][4];
    {
      const u16* Qb = qk + (size_t)tokq * QKN + h * 128;
#pragma unroll
      for (int j = 0; j < 2; ++j) {
        const u16* Qr = Qb + (size_t)(wave * 32 + j * 16 + l15) * QKN + quad * 8;
#pragma unroll
        for (int ks = 0; ks < 4; ++ks)
          qf[j][ks] = *(const bf16x8*)(Qr + ks * 32);
      }
    }

    f32x4 acc_o[8][2] = {};
    float mrun[2] = {-1e30f, -1e30f};
    float lrun[2] = {0.f, 0.f};

    __syncthreads();   // prologue: Ks[0]/Vs[0] staged (vmcnt drained here)

    for (int jt = 0; jt <= jt_end; ++jt) {
      // prefetch next K/V tiles into the other buffers
      if (jt < jt_end) {
        stageK(jt + 1, (jt + 1) & 1);
        stageV(jt + 1, (jt + 1) & 1);
      }

      // ---- S^T = K * Q^T (kf from LDS) ----
      f32x4 acc_s[4][2] = {};
      {
        const u16* Kt = Ks[jt & 1];
        bf16x8 kf[4][4];
#pragma unroll
        for (int i = 0; i < 4; ++i) {
          const u16* Kr = Kt + (i * 16 + l15) * 128;
#pragma unroll
          for (int ks = 0; ks < 4; ++ks) {
            int c = quad + ks * 4;
            kf[i][ks] = *(const bf16x8*)(Kr + (((c & 8) | ((c & 7) ^ rx)) << 3));
          }
        }
#pragma unroll
        for (int ks = 0; ks < 4; ++ks)
#pragma unroll
          for (int i = 0; i < 4; ++i)
#pragma unroll
            for (int j = 0; j < 2; ++j)
              acc_s[i][j] = __builtin_amdgcn_mfma_f32_16x16x32_bf16(kf[i][ks], qf[j][ks],
                                                                    acc_s[i][j], 0, 0, 0);
      }

      // ---- online softmax (log2 domain; per-lane state; q fixed per lane) ----
      const bool need_mask = (jt >= 2 * qt);
#pragma unroll
      for (int j = 0; j < 2; ++j) {
        int ql = wave * 32 + j * 16 + l15;  // q local in 128-tile
        int qg = qt * 128 + ql;             // q in window
        float vmax = -1e30f;
#pragma unroll
        for (int i = 0; i < 4; ++i)
#pragma unroll
          for (int t = 0; t < 4; ++t) {
            float s = acc_s[i][j][t] * CL2E;
            if (need_mask) {
              int kg = jt * 64 + i * 16 + quad * 4 + t;
              if (kg > qg) s = -1e30f;
            }
            acc_s[i][j][t] = s;
            vmax = fmaxf(vmax, s);
          }
        vmax = fmaxf(vmax, __shfl_xor(vmax, 16));
        vmax = fmaxf(vmax, __shfl_xor(vmax, 32));
        // defer-max (T13): rescale only when max outgrew running max by > THR
        if (__any(vmax > mrun[j] + THR)) {
          float mnew = fmaxf(mrun[j], vmax);
          float alpha = __builtin_amdgcn_exp2f(mrun[j] - mnew);
          mrun[j] = mnew;
          lrun[j] *= alpha;
#pragma unroll
          for (int i2 = 0; i2 < 8; ++i2)
#pragma unroll
            for (int t = 0; t < 4; ++t)
              acc_o[i2][j][t] *= alpha;
        }
        float mnew = mrun[j];
        float vsum = 0.f;
#pragma unroll
        for (int i = 0; i < 4; ++i) {
          float p0 = __builtin_amdgcn_exp2f(acc_s[i][j][0] - mnew);
          float p1 = __builtin_amdgcn_exp2f(acc_s[i][j][1] - mnew);
          float p2 = __builtin_amdgcn_exp2f(acc_s[i][j][2] - mnew);
          float p3 = __builtin_amdgcn_exp2f(acc_s[i][j][3] - mnew);
          vsum += (p0 + p1) + (p2 + p3);
          uint2 pk;
          pk.x = cvt_pk_bf16(p0, p1);
          pk.y = cvt_pk_bf16(p2, p3);
          int kk = i * 16 + quad * 4;
          *(uint2*)((char*)Ps + ql * 128 + (((kk >> 3) ^ (ql & 7)) << 4) + ((kk & 7) << 1)) = pk;
        }
        vsum += __shfl_xor(vsum, 16);
        vsum += __shfl_xor(vsum, 32);
        lrun[j] += vsum;
      }
      __syncthreads();  // Ps written (+ jt+1 stages drained)

      // ---- O^T += V^T * P^T ----
      const u16* Vtile = Vs[jt & 1];
#pragma unroll
      for (int ks = 0; ks < 2; ++ks) {
        int kc = (ks * 32 + quad * 8) >> 3;
        bf16x8 pf[2];
#pragma unroll
        for (int j = 0; j < 2; ++j) {
          int ql = wave * 32 + j * 16 + l15;
          pf[j] = *(const bf16x8*)((char*)Ps + ql * 128 + ((kc ^ (ql & 7)) << 4));
        }
#pragma unroll
        for (int i2 = 0; i2 < 8; ++i2) {
          int d = i2 * 16 + l15;
          bf16x8 vf = *(const bf16x8*)((char*)Vtile + d * 128 + ((kc ^ (d & 7)) << 4));
#pragma unroll
          for (int j = 0; j < 2; ++j)
            acc_o[i2][j] = __builtin_amdgcn_mfma_f32_16x16x32_bf16(vf, pf[j], acc_o[i2][j], 0, 0, 0);
        }
      }
      __syncthreads();  // protect Ks/Vs/Ps for next jt
    }

    // ---- epilogue: O^T C-layout -> attn_out[tok][h*128+d] ----
#pragma unroll
    for (int j = 0; j < 2; ++j) {
      float inv = 1.0f / lrun[j];
      int ql = wave * 32 + j * 16 + l15;
      u16* orow = attn_out + (size_t)(tokq + ql) * DM + h * 128;
#pragma unroll
      for (int i2 = 0; i2 < 8; ++i2) {
        int d = i2 * 16 + quad * 4;
        uint2 pk;
        pk.x = cvt_pk_bf16(acc_o[i2][j][0] * inv, acc_o[i2][j][1] * inv);
        pk.y = cvt_pk_bf16(acc_o[i2][j][2] * inv, acc_o[i2][j][3] * inv);
        *(uint2*)(orow + d) = pk;
      }
    }
    // no barrier needed: after the last loop barrier, waves touch only
    // registers/global; next half's stages rewrite LDS safely.
  }
}

// ---------------- launch ----------------

extern "C" void kernel_launch(void* const* d_in, const int* in_sizes, int n_in,
                              void* d_out, int out_size, void* d_ws, size_t ws_size,
                              hipStream_t stream) {
  const float* x = (const float*)d_in[0];
  const float* W_qkv = (const float*)d_in[1];
  const float* b_qkv = (const float*)d_in[2];
  const float* W_out = (const float*)d_in[3];
  const float* b_out = (const float*)d_in[4];
  float* out = (float*)d_out;

  char* w = (char*)d_ws;
  u16* xb = (u16*)w;                              // 32MB [8192][2048]; reused as attn_out
  u16* wqkvT = (u16*)(w + (32u << 20));           // 24MB [6144][2048]
  u16* woutT = (u16*)(w + (56u << 20));           // 8MB  [2048][2048]
  u16* qk = (u16*)(w + (64u << 20));              // 64MB [8192][4096]  (Q,K)
  u16* vtb = (u16*)(w + (128u << 20));            // 32MB [2048][8192]  (V^T)

  cast_f32_bf16<<<8192, 256, 0, stream>>>((const float4*)x, (uint4*)xb);
  transpose_cast<<<dim3(96, 32), 256, 0, stream>>>(W_qkv, wqkvT, 2048, 6144);
  transpose_cast<<<dim3(32, 32), 256, 0, stream>>>(W_out, woutT, 2048, 2048);
  gemm_bt<u16><<<dim3(48, 64), 256, 0, stream>>>(xb, wqkvT, b_qkv, qk, vtb,
                                                 8192, 6144, 2048, 4096, 4096);
  attn_win<<<dim3(2, 8, 32), 256, 0, stream>>>(qk, vtb, xb);
  gemm_bt<float><<<dim3(16, 64), 256, 0, stream>>>(xb, woutT, b_out, out, vtb,
                                                   8192, 2048, 2048, 2048, 1 << 28);
}

// Round 9
// 481.465 us; speedup vs baseline: 1.1097x; 1.0076x over previous
//
#include <hip/hip_runtime.h>
#include <stdint.h>

// WindowedAttn on MI355X (gfx950)
// Pipeline: fused prep (cast x->bf16 + transpose W_qkv,W_out)
//           | GEMM1 -> Q,K into qk[tok][4096] AND V transposed into vt[d][tok]
//           | flash attention per 128-q tile (S^T / O^T trick)
//           | GEMM2 (fp32 out)
// GEMMs: 128x128 block tile, BK=64, global_load_lds width=16, XOR-swizzled LDS.
// R8: attn K-tile staged in LDS (dbuf) + qt-pairing (uniform 10 jt/block): -49us.
// R9: (a) attn counted-wait raw barriers -- barrier1 waits lgkmcnt(0) ONLY so
// the K/V prefetch issued at top-of-jt stays in flight across it (syncthreads'
// vmcnt(0) drain was stalling every wave twice per jt); barrier2 keeps the full
// drain (next QK reads the staged tiles). (b) prep fused into one launch.
// Softmax: log2-domain + v_cvt_pk_bf16_f32 + defer-max THR=12 (R6).

typedef unsigned short u16;
typedef unsigned int u32;
typedef __attribute__((ext_vector_type(8))) short bf16x8;   // 8 bf16 = 4 VGPRs
typedef __attribute__((ext_vector_type(4))) float f32x4;

#define QKN 4096   // Q,K buffer row stride
#define DM 2048

__device__ __forceinline__ u16 f2b(float f) {
  u32 u = __builtin_bit_cast(u32, f);
  u32 r = (u + 0x7fffu + ((u >> 16) & 1u)) >> 16;  // RNE
  return (u16)r;
}

// pack two f32 -> two bf16 (RNE), lo in bits[15:0]
__device__ __forceinline__ u32 cvt_pk_bf16(float lo, float hi) {
  u32 r;
  asm("v_cvt_pk_bf16_f32 %0, %1, %2" : "=v"(r) : "v"(lo), "v"(hi));
  return r;
}

__device__ __forceinline__ void gload_lds16(const void* g, void* l) {
  __builtin_amdgcn_global_load_lds((const __attribute__((address_space(1))) void*)g,
                                   (__attribute__((address_space(3))) void*)l,
                                   16, 0, 0);
}

// ---------------- fused prep ----------------
// blocks [0,8192): cast x (f32) -> xb (bf16), 8 elems/thread
// blocks [8192,11264): transpose W_qkv (2048x6144) -> wqkvT (6144x2048 bf16)
// blocks [11264,12288): transpose W_out (2048x2048) -> woutT
// Branch is block-uniform; the three BW-bound phases overlap on the device.

__global__ __launch_bounds__(256) void prep(const float4* __restrict__ x,
                                            uint4* __restrict__ xb,
                                            const float* __restrict__ W_qkv,
                                            u16* __restrict__ wqkvT,
                                            const float* __restrict__ W_out,
                                            u16* __restrict__ woutT) {
  __shared__ u16 tile[64][65];
  const int bid = blockIdx.x;
  if (bid < 8192) {
    int idx = bid * 256 + threadIdx.x;
    float4 a = x[2 * idx];
    float4 b = x[2 * idx + 1];
    uint4 r;
    r.x = (u32)f2b(a.x) | ((u32)f2b(a.y) << 16);
    r.y = (u32)f2b(a.z) | ((u32)f2b(a.w) << 16);
    r.z = (u32)f2b(b.x) | ((u32)f2b(b.y) << 16);
    r.w = (u32)f2b(b.z) | ((u32)f2b(b.w) << 16);
    xb[idx] = r;
    return;
  }
  const float* W;
  u16* Wt;
  int N, bx, by;
  if (bid < 11264) {
    int b = bid - 8192;
    W = W_qkv; Wt = wqkvT; N = 6144; bx = b % 96; by = b / 96;
  } else {
    int b = bid - 11264;
    W = W_out; Wt = woutT; N = 2048; bx = b & 31; by = b >> 5;
  }
  const int K = 2048;
  int tx = threadIdx.x & 63;
  int ty = threadIdx.x >> 6;
  int n0 = bx * 64;
  int k0 = by * 64;
#pragma unroll
  for (int r = 0; r < 64; r += 4)
    tile[r + ty][tx] = f2b(W[(size_t)(k0 + r + ty) * N + n0 + tx]);
  __syncthreads();
#pragma unroll
  for (int r = 0; r < 64; r += 4)
    Wt[(size_t)(n0 + r + ty) * K + k0 + tx] = tile[tx][r + ty];
}

// ---------------- GEMM: C[M][N] = A[M][K] * Bt[N][K]^T + bias ----------------
// block 256 = 4 waves (2x2 of 64x64), 4x4 16x16x32 mfma per wave.
// Columns >= vstart are written TRANSPOSED to vt[col-vstart][row] (V^T for attn);
// n0 is 128-aligned so the branch is uniform per block.

template <typename TO>
__global__ __launch_bounds__(256, 3) void gemm_bt(const u16* __restrict__ A,
                                                  const u16* __restrict__ Bt,
                                                  const float* __restrict__ bias,
                                                  TO* __restrict__ C,
                                                  u16* __restrict__ vt,
                                                  int M, int N, int K,
                                                  int crstride, int vstart) {
  __shared__ u16 As[128 * 64];
  __shared__ u16 Bs[128 * 64];
  const int tid = threadIdx.x;
  const int lane = tid & 63;
  const int wave = tid >> 6;
  const int quad = lane >> 4;
  const int l15 = lane & 15;
  const int m0 = blockIdx.y * 128;
  const int n0 = blockIdx.x * 128;
  const int wm = (wave & 1) * 64;
  const int wn = (wave >> 1) * 64;

  f32x4 acc[4][4] = {};

  for (int k0 = 0; k0 < K; k0 += 64) {
    // stage A,B tiles: row = 128B = 8 chunks of 16B; stored chunk c' = c ^ (row&7)
#pragma unroll
    for (int i = 0; i < 4; ++i) {
      int sb = wave * 256 + i * 64;     // wave-uniform slot base
      int s = sb + lane;                // slot = row*8 + c'
      int m = s >> 3;
      int c = (s & 7) ^ (m & 7);        // global chunk to fetch for this slot
      gload_lds16(A + (size_t)(m0 + m) * K + (k0 + c * 8), As + sb * 8);
      gload_lds16(Bt + (size_t)(n0 + m) * K + (k0 + c * 8), Bs + sb * 8);
    }
    __syncthreads();
#pragma unroll
    for (int ks = 0; ks < 2; ++ks) {
      bf16x8 af[4], bf[4];
#pragma unroll
      for (int i = 0; i < 4; ++i) {
        int m = wm + i * 16 + l15;
        af[i] = *(const bf16x8*)(As + m * 64 + (((ks * 4 + quad) ^ (m & 7)) << 3));
        int n = wn + i * 16 + l15;
        bf[i] = *(const bf16x8*)(Bs + n * 64 + (((ks * 4 + quad) ^ (n & 7)) << 3));
      }
#pragma unroll
      for (int i = 0; i < 4; ++i)
#pragma unroll
        for (int j = 0; j < 4; ++j)
          acc[i][j] = __builtin_amdgcn_mfma_f32_16x16x32_bf16(af[i], bf[j], acc[i][j], 0, 0, 0);
    }
    __syncthreads();
  }

  // epilogue: D row=(quad*4+t), col=l15 (m89-verified)
  if (n0 >= vstart) {
    // V block: write transposed vt[d][token], 4 consecutive tokens packed -> 8B store
#pragma unroll
    for (int j = 0; j < 4; ++j) {
      int col = n0 + wn + j * 16 + l15;
      float bv = bias[col];
      u16* vcol = vt + (size_t)(col - vstart) * 8192;
#pragma unroll
      for (int i = 0; i < 4; ++i) {
        int row = m0 + wm + i * 16 + quad * 4;
        uint2 pk;
        pk.x = (u32)f2b(acc[i][j][0] + bv) | ((u32)f2b(acc[i][j][1] + bv) << 16);
        pk.y = (u32)f2b(acc[i][j][2] + bv) | ((u32)f2b(acc[i][j][3] + bv) << 16);
        *(uint2*)(vcol + row) = pk;
      }
    }
  } else {
#pragma unroll
    for (int j = 0; j < 4; ++j) {
      int col = n0 + wn + j * 16 + l15;
      float bv = bias[col];
#pragma unroll
      for (int i = 0; i < 4; ++i) {
        int row = m0 + wm + i * 16 + quad * 4;
#pragma unroll
        for (int t = 0; t < 4; ++t) {
          float v = acc[i][j][t] + bv;
          if constexpr (sizeof(TO) == 2)
            C[(size_t)(row + t) * crstride + col] = (TO)f2b(v);
          else
            C[(size_t)(row + t) * crstride + col] = (TO)v;
        }
      }
    }
  }
}

// ---------------- attention ----------------
// One block per (pair, win, b*16+h); pair x runs q-tiles {x, 3-x} sequentially
// (uniform 10 jt-units per block). kk-tiles of 64.
// S^T = K * Q^T: kf from Ks LDS [kk=64][d=128] (16 chunks/row, swizzled
// c' = (c&8)|((c&7)^(row&7))), staged via global_load_lds, double-buffered.
// O^T += V^T * P^T: vf from Vs LDS [d][kk] (8 chunks/row, c^(d&7)); pf from Ps.
// Barriers (counted-wait, m201 pattern): barrier1 waits lgkmcnt(0) only (Ps
// visible) -- the 8 stage loads/thread stay in flight; barrier2 waits
// vmcnt(0)+lgkmcnt(0) (stages landed for next jt's QK). The prefetch thus gets
// the full jt (QK+SM+PV) to cover HBM/L2 latency instead of QK+SM only.

__global__ __launch_bounds__(256, 2) void attn_win(const u16* __restrict__ qk,
                                                   const u16* __restrict__ vt,
                                                   u16* __restrict__ attn_out) {
  __shared__ u16 Ks[2][8192];   // [kk=64][d=128], 16 chunks/row, dbuf (32KB)
  __shared__ u16 Vs[2][8192];   // [d=128][kk=64],  8 chunks/row, dbuf (32KB)
  __shared__ u16 Ps[128 * 64];  // [q][kk], chunk ^ (q&7) (16KB)
  const int tid = threadIdx.x;
  const int lane = tid & 63;
  const int wave = tid >> 6;
  const int quad = lane >> 4;
  const int l15 = lane & 15;
  const int win = blockIdx.y;       // 0..7
  const int b = blockIdx.z >> 4;
  const int h = blockIdx.z & 15;
  const int tokw = b * 4096 + win * 512;
  const float CL2E = 0.12751743f;   // (1/sqrt(128)) * log2(e)
  const float THR = 12.0f;          // defer-max threshold (log2): P <= 2^12

  // stage V^T tile (rows d, 8x16B chunks/row, src chunk = c' ^ (d&7))
  auto stageV = [&](int jt, int buf) {
    const u16* vbase = vt + (size_t)(h * 128) * 8192 + (tokw + jt * 64);
    char* dst0 = (char*)Vs[buf] + wave * 1024;
#pragma unroll
    for (int it = 0; it < 4; ++it) {
      int ch = it * 256 + wave * 64 + lane;   // 1024 chunks of 16B
      int row = ch >> 3;
      int c = (ch & 7) ^ (row & 7);
      gload_lds16(vbase + (size_t)row * 8192 + c * 8, dst0 + it * 4096);
    }
  };
  // stage K tile (rows kk, 16x16B chunks/row, src chunk = (c'&8)|((c'&7)^(kk&7)))
  auto stageK = [&](int jt, int buf) {
    const u16* kbase = qk + (size_t)(tokw + jt * 64) * QKN + 2048 + h * 128;
    char* dst0 = (char*)Ks[buf] + wave * 1024;
#pragma unroll
    for (int it = 0; it < 4; ++it) {
      int ch = it * 256 + wave * 64 + lane;   // 1024 chunks of 16B
      int row = ch >> 4;
      int c16 = ch & 15;
      int c = (c16 & 8) | ((c16 & 7) ^ (row & 7));
      gload_lds16(kbase + (size_t)row * QKN + c * 8, dst0 + it * 4096);
    }
  };

  const int rx = l15 & 7;   // row&7 for all fragment rows (i*16+l15)

  for (int half = 0; half < 2; ++half) {
    const int qt = half == 0 ? (int)blockIdx.x : 3 - (int)blockIdx.x;  // {x,3-x}
    const int tokq = tokw + qt * 128;
    const int jt_end = 2 * qt + 1;

    stageK(0, 0);
    stageV(0, 0);

    // Q fragments (registers for the whole half)
    bf16x8 qf[2][4];
    {
      const u16* Qb = qk + (size_t)tokq * QKN + h * 128;
#pragma unroll
      for (int j = 0; j < 2; ++j) {
        const u16* Qr = Qb + (size_t)(wave * 32 + j * 16 + l15) * QKN + quad * 8;
#pragma unroll
        for (int ks = 0; ks < 4; ++ks)
          qf[j][ks] = *(const bf16x8*)(Qr + ks * 32);
      }
    }

    f32x4 acc_o[8][2] = {};
    float mrun[2] = {-1e30f, -1e30f};
    float lrun[2] = {0.f, 0.f};

    __syncthreads();   // prologue: Ks[0]/Vs[0] staged (full drain here is fine)

    for (int jt = 0; jt <= jt_end; ++jt) {
      // prefetch next K/V tiles into the other buffers (stay in flight past
      // barrier1; drained at barrier2)
      if (jt < jt_end) {
        stageK(jt + 1, (jt + 1) & 1);
        stageV(jt + 1, (jt + 1) & 1);
      }

      // ---- S^T = K * Q^T (kf from LDS) ----
      f32x4 acc_s[4][2] = {};
      {
        const u16* Kt = Ks[jt & 1];
        bf16x8 kf[4][4];
#pragma unroll
        for (int i = 0; i < 4; ++i) {
          const u16* Kr = Kt + (i * 16 + l15) * 128;
#pragma unroll
          for (int ks = 0; ks < 4; ++ks) {
            int c = quad + ks * 4;
            kf[i][ks] = *(const bf16x8*)(Kr + (((c & 8) | ((c & 7) ^ rx)) << 3));
          }
        }
#pragma unroll
        for (int ks = 0; ks < 4; ++ks)
#pragma unroll
          for (int i = 0; i < 4; ++i)
#pragma unroll
            for (int j = 0; j < 2; ++j)
              acc_s[i][j] = __builtin_amdgcn_mfma_f32_16x16x32_bf16(kf[i][ks], qf[j][ks],
                                                                    acc_s[i][j], 0, 0, 0);
      }

      // ---- online softmax (log2 domain; per-lane state; q fixed per lane) ----
      const bool need_mask = (jt >= 2 * qt);
#pragma unroll
      for (int j = 0; j < 2; ++j) {
        int ql = wave * 32 + j * 16 + l15;  // q local in 128-tile
        int qg = qt * 128 + ql;             // q in window
        float vmax = -1e30f;
#pragma unroll
        for (int i = 0; i < 4; ++i)
#pragma unroll
          for (int t = 0; t < 4; ++t) {
            float s = acc_s[i][j][t] * CL2E;
            if (need_mask) {
              int kg = jt * 64 + i * 16 + quad * 4 + t;
              if (kg > qg) s = -1e30f;
            }
            acc_s[i][j][t] = s;
            vmax = fmaxf(vmax, s);
          }
        vmax = fmaxf(vmax, __shfl_xor(vmax, 16));
        vmax = fmaxf(vmax, __shfl_xor(vmax, 32));
        // defer-max (T13): rescale only when max outgrew running max by > THR
        if (__any(vmax > mrun[j] + THR)) {
          float mnew = fmaxf(mrun[j], vmax);
          float alpha = __builtin_amdgcn_exp2f(mrun[j] - mnew);
          mrun[j] = mnew;
          lrun[j] *= alpha;
#pragma unroll
          for (int i2 = 0; i2 < 8; ++i2)
#pragma unroll
            for (int t = 0; t < 4; ++t)
              acc_o[i2][j][t] *= alpha;
        }
        float mnew = mrun[j];
        float vsum = 0.f;
#pragma unroll
        for (int i = 0; i < 4; ++i) {
          float p0 = __builtin_amdgcn_exp2f(acc_s[i][j][0] - mnew);
          float p1 = __builtin_amdgcn_exp2f(acc_s[i][j][1] - mnew);
          float p2 = __builtin_amdgcn_exp2f(acc_s[i][j][2] - mnew);
          float p3 = __builtin_amdgcn_exp2f(acc_s[i][j][3] - mnew);
          vsum += (p0 + p1) + (p2 + p3);
          uint2 pk;
          pk.x = cvt_pk_bf16(p0, p1);
          pk.y = cvt_pk_bf16(p2, p3);
          int kk = i * 16 + quad * 4;
          *(uint2*)((char*)Ps + ql * 128 + (((kk >> 3) ^ (ql & 7)) << 4) + ((kk & 7) << 1)) = pk;
        }
        vsum += __shfl_xor(vsum, 16);
        vsum += __shfl_xor(vsum, 32);
        lrun[j] += vsum;
      }
      // barrier1: Ps visible to all waves; stage loads NOT drained (counted wait)
      asm volatile("s_waitcnt lgkmcnt(0)" ::: "memory");
      __builtin_amdgcn_s_barrier();

      // ---- O^T += V^T * P^T ----
      const u16* Vtile = Vs[jt & 1];
#pragma unroll
      for (int ks = 0; ks < 2; ++ks) {
        int kc = (ks * 32 + quad * 8) >> 3;
        bf16x8 pf[2];
#pragma unroll
        for (int j = 0; j < 2; ++j) {
          int ql = wave * 32 + j * 16 + l15;
          pf[j] = *(const bf16x8*)((char*)Ps + ql * 128 + ((kc ^ (ql & 7)) << 4));
        }
#pragma unroll
        for (int i2 = 0; i2 < 8; ++i2) {
          int d = i2 * 16 + l15;
          bf16x8 vf = *(const bf16x8*)((char*)Vtile + d * 128 + ((kc ^ (d & 7)) << 4));
#pragma unroll
          for (int j = 0; j < 2; ++j)
            acc_o[i2][j] = __builtin_amdgcn_mfma_f32_16x16x32_bf16(vf, pf[j], acc_o[i2][j], 0, 0, 0);
        }
      }
      // barrier2: stages for jt+1 landed (vmcnt), all reads of this jt done
      asm volatile("s_waitcnt vmcnt(0) lgkmcnt(0)" ::: "memory");
      __builtin_amdgcn_s_barrier();
    }

    // ---- epilogue: O^T C-layout -> attn_out[tok][h*128+d] ----
#pragma unroll
    for (int j = 0; j < 2; ++j) {
      float inv = 1.0f / lrun[j];
      int ql = wave * 32 + j * 16 + l15;
      u16* orow = attn_out + (size_t)(tokq + ql) * DM + h * 128;
#pragma unroll
      for (int i2 = 0; i2 < 8; ++i2) {
        int d = i2 * 16 + quad * 4;
        uint2 pk;
        pk.x = cvt_pk_bf16(acc_o[i2][j][0] * inv, acc_o[i2][j][1] * inv);
        pk.y = cvt_pk_bf16(acc_o[i2][j][2] * inv, acc_o[i2][j][3] * inv);
        *(uint2*)(orow + d) = pk;
      }
    }
    // no barrier needed: after the last loop barrier, waves touch only
    // registers/global; next half's stages rewrite LDS safely.
  }
}

// ---------------- launch ----------------

extern "C" void kernel_launch(void* const* d_in, const int* in_sizes, int n_in,
                              void* d_out, int out_size, void* d_ws, size_t ws_size,
                              hipStream_t stream) {
  const float* x = (const float*)d_in[0];
  const float* W_qkv = (const float*)d_in[1];
  const float* b_qkv = (const float*)d_in[2];
  const float* W_out = (const float*)d_in[3];
  const float* b_out = (const float*)d_in[4];
  float* out = (float*)d_out;

  char* w = (char*)d_ws;
  u16* xb = (u16*)w;                              // 32MB [8192][2048]; reused as attn_out
  u16* wqkvT = (u16*)(w + (32u << 20));           // 24MB [6144][2048]
  u16* woutT = (u16*)(w + (56u << 20));           // 8MB  [2048][2048]
  u16* qk = (u16*)(w + (64u << 20));              // 64MB [8192][4096]  (Q,K)
  u16* vtb = (u16*)(w + (128u << 20));            // 32MB [2048][8192]  (V^T)

  prep<<<12288, 256, 0, stream>>>((const float4*)x, (uint4*)xb, W_qkv, wqkvT,
                                  W_out, woutT);
  gemm_bt<u16><<<dim3(48, 64), 256, 0, stream>>>(xb, wqkvT, b_qkv, qk, vtb,
                                                 8192, 6144, 2048, 4096, 4096);
  attn_win<<<dim3(2, 8, 32), 256, 0, stream>>>(qk, vtb, xb);
  gemm_bt<float><<<dim3(16, 64), 256, 0, stream>>>(xb, woutT, b_out, out, vtb,
                                                   8192, 2048, 2048, 2048, 1 << 28);
}